// Round 1
// baseline (599.059 us; speedup 1.0000x reference)
//
#include <hip/hip_runtime.h>
#include <stdint.h>

typedef float f32x4 __attribute__((ext_vector_type(4)));
typedef short bf16x8 __attribute__((ext_vector_type(8)));
typedef int   i32x4  __attribute__((ext_vector_type(4)));

#define IN_DIM   25088
#define OUT_DIM  4096
#define BATCH    64
#define SPLITS   28
#define KBLK     64
#define NBLK     14        // KBLK*NBLK = 896 = IN_DIM/SPLITS exactly
#define WG_N     128

#define CONV_BLOCKS 784    // convert_x part: 784*256*8 = 64*25088 floats
#define INIT_BLOCKS 64     // out-init part: 64*256*16 = 64*4096 floats

// fp32 -> bf16 bits, round-to-nearest-even
__device__ __forceinline__ uint32_t f2bf(float f) {
    uint32_t u = __builtin_bit_cast(uint32_t, f);
    return (u + 0x7FFFu + ((u >> 16) & 1u)) >> 16;
}
__device__ __forceinline__ uint32_t pack2(float a, float b) {
    return f2bf(a) | (f2bf(b) << 16);
}

// ---- kernel 1 (fused prep): x fp32 -> bf16 into d_ws, AND out = bias ----
__global__ __launch_bounds__(256) void prep(const float* __restrict__ x,
                                            const float* __restrict__ bias,
                                            uint32_t* __restrict__ xb,
                                            float* __restrict__ out) {
    if (blockIdx.x < CONV_BLOCKS) {
        const size_t i = blockIdx.x * 256 + threadIdx.x;  // 8 floats -> 4 u32
        const float4 v0 = *(const float4*)(x + i * 8);
        const float4 v1 = *(const float4*)(x + i * 8 + 4);
        uint4 o;
        o.x = pack2(v0.x, v0.y); o.y = pack2(v0.z, v0.w);
        o.z = pack2(v1.x, v1.y); o.w = pack2(v1.z, v1.w);
        *(uint4*)(xb + i * 4) = o;
    } else {
        // out[b][o] = bias[o]; 16384 threads x 4 float4 = 64*4096 floats
        const size_t g = (size_t)(blockIdx.x - CONV_BLOCKS) * 256 + threadIdx.x;
        const float4* b4 = (const float4*)bias;
        float4* o4 = (float4*)out;
        #pragma unroll
        for (int r = 0; r < 4; ++r) {
            const size_t j = g * 4 + r;
            o4[j] = b4[j & (OUT_DIM / 4 - 1)];
        }
    }
}

// ---- kernel 2: main GEMM, BARRIER-FREE main loop ----
// Each lane loads the labels for exactly its own MFMA B-fragment
// (8 consecutive k = 32 contiguous bytes), dequantizes via the LDS pair
// table straight into registers, and loads its x A-fragments directly
// from L2-resident xb. No W/x LDS tiles -> no __syncthreads in the loop
// -> the compiler's pre-barrier "s_waitcnt vmcnt(0)" can never drain the
// label prefetch; the HBM stream stays in flight across the MFMA phase.
__global__ __launch_bounds__(256) void qlinear_main(
    const int*      __restrict__ labels,    // [4096, 25088] int32 in [0,32)
    const float*    __restrict__ centroids, // [32]
    const uint16_t* __restrict__ xb,        // [64, 25088] bf16 (precomputed)
    float*          __restrict__ out)       // [64, 4096] fp32, pre-init = bias
{
    __shared__ __align__(16) uint32_t table[1024];  // pair dequant table, 4 KB

    const int t     = threadIdx.x;
    const int wgn   = blockIdx.x & 31;      // OUT_DIM / WG_N = 32 tiles
    const int split = blockIdx.x >> 5;      // 0..27
    const int o0    = wgn * WG_N;
    const int kbase = split * (KBLK * NBLK);

    // pair table: entry i = bf16(c[i&31]) | bf16(c[i>>5])<<16 (low = earlier k)
    #pragma unroll
    for (int e = 0; e < 4; ++e) {
        const int i = t + 256 * e;
        table[i] = f2bf(centroids[i & 31]) | (f2bf(centroids[i >> 5]) << 16);
    }
    __syncthreads();   // the ONLY barrier in this kernel

    const int lane = t & 63;
    const int wave = t >> 6;      // 0..3 -> 32 out-rows each
    const int ln   = lane & 15;
    const int lq   = lane >> 4;   // 0..3 ; frag k = lq*8 + j

    // per-lane label pointers: the two B-frag rows this lane owns (nt=0,1)
    const int* lp0 = labels + (size_t)(o0 + wave * 32 +  0 + ln) * IN_DIM + kbase + lq * 8;
    const int* lp1 = labels + (size_t)(o0 + wave * 32 + 16 + ln) * IN_DIM + kbase + lq * 8;

    // per-lane x pointers: the four A-frag rows (batch m = mt*16 + ln)
    const uint16_t* xp[4];
    #pragma unroll
    for (int mt = 0; mt < 4; ++mt)
        xp[mt] = xb + (size_t)(mt * 16 + ln) * IN_DIM + kbase + lq * 8;

    f32x4 acc[4][2] = {};   // [batch 16s][out 16s]

    // prologue: labels for blk 0 (nontemporal: 411 MB read-once stream,
    // evict-first keeps xb hot in L2)
    i32x4 cur[2][2][2];     // [nt][ks][half] : 8 consecutive k per (nt,ks)
    #pragma unroll
    for (int nt = 0; nt < 2; ++nt) {
        const int* lp = nt ? lp1 : lp0;
        #pragma unroll
        for (int ks = 0; ks < 2; ++ks) {
            const i32x4* p = (const i32x4*)(lp + ks * 32);
            cur[nt][ks][0] = __builtin_nontemporal_load(p);
            cur[nt][ks][1] = __builtin_nontemporal_load(p + 1);
        }
    }

    for (int blk = 0; blk < NBLK; ++blk) {
        const int koff = blk * KBLK;

        // (1) x A-frags for THIS step, issued FIRST: vmcnt retires in issue
        //     order, so these fast L2 hits never wait on the HBM labels
        //     issued after them.
        bf16x8 a[2][4];   // [ks][mt]
        #pragma unroll
        for (int ks = 0; ks < 2; ++ks)
            #pragma unroll
            for (int mt = 0; mt < 4; ++mt)
                a[ks][mt] = *(const bf16x8*)(xp[mt] + koff + ks * 32);

        // (2) label prefetch for NEXT step — stays in flight across the
        //     entire dequant+MFMA phase below (no barrier ever drains it)
        i32x4 nxt[2][2][2];
        if (blk + 1 < NBLK) {
            #pragma unroll
            for (int nt = 0; nt < 2; ++nt) {
                const int* lp = (nt ? lp1 : lp0) + koff + KBLK;
                #pragma unroll
                for (int ks = 0; ks < 2; ++ks) {
                    const i32x4* p = (const i32x4*)(lp + ks * 32);
                    nxt[nt][ks][0] = __builtin_nontemporal_load(p);
                    nxt[nt][ks][1] = __builtin_nontemporal_load(p + 1);
                }
            }
        }

        // (3) dequant THIS step's labels -> B-frags in registers, (4) MFMA
        #pragma unroll
        for (int ks = 0; ks < 2; ++ks) {
            #pragma unroll
            for (int nt = 0; nt < 2; ++nt) {
                union { bf16x8 v; uint32_t u[4]; } b;
                const i32x4 v0 = cur[nt][ks][0];
                const i32x4 v1 = cur[nt][ks][1];
                b.u[0] = table[(uint32_t)v0.x | ((uint32_t)v0.y << 5)];
                b.u[1] = table[(uint32_t)v0.z | ((uint32_t)v0.w << 5)];
                b.u[2] = table[(uint32_t)v1.x | ((uint32_t)v1.y << 5)];
                b.u[3] = table[(uint32_t)v1.z | ((uint32_t)v1.w << 5)];
                #pragma unroll
                for (int mt = 0; mt < 4; ++mt)
                    acc[mt][nt] = __builtin_amdgcn_mfma_f32_16x16x32_bf16(
                        a[ks][mt], b.v, acc[mt][nt], 0, 0, 0);
            }
        }

        // rotate prefetch registers
        if (blk + 1 < NBLK) {
            #pragma unroll
            for (int nt = 0; nt < 2; ++nt)
                #pragma unroll
                for (int ks = 0; ks < 2; ++ks) {
                    cur[nt][ks][0] = nxt[nt][ks][0];
                    cur[nt][ks][1] = nxt[nt][ks][1];
                }
        }
    }

    // ---- epilogue: C/D layout col=lane&15 (out), row=(lane>>4)*4+reg (batch).
    // out is only 1 MB and L2/IF-resident: device-scope fp32 atomics are cheap
    // and delete the partials round-trip + a third kernel.
    #pragma unroll
    for (int mt = 0; mt < 4; ++mt)
        #pragma unroll
        for (int nt = 0; nt < 2; ++nt) {
            const int o = o0 + wave * 32 + nt * 16 + ln;
            #pragma unroll
            for (int r = 0; r < 4; ++r)
                atomicAdd(out + (size_t)(mt * 16 + lq * 4 + r) * OUT_DIM + o,
                          acc[mt][nt][r]);
        }
}

extern "C" void kernel_launch(void* const* d_in, const int* in_sizes, int n_in,
                              void* d_out, int out_size, void* d_ws, size_t ws_size,
                              hipStream_t stream) {
    const float* x         = (const float*)d_in[0];
    const int*   labels    = (const int*)d_in[1];
    const float* centroids = (const float*)d_in[2];
    const float* bias      = (const float*)d_in[3];
    float* out = (float*)d_out;

    uint32_t* xb = (uint32_t*)d_ws;   // 3.2 MB bf16 x

    prep<<<CONV_BLOCKS + INIT_BLOCKS, 256, 0, stream>>>(x, bias, xb, out);
    qlinear_main<<<32 * SPLITS, 256, 0, stream>>>(labels, centroids,
                                                  (const uint16_t*)xb, out);
}

// Round 2
// 553.383 us; speedup vs baseline: 1.0825x; 1.0825x over previous
//
#include <hip/hip_runtime.h>
#include <stdint.h>

typedef float f32x4 __attribute__((ext_vector_type(4)));
typedef short bf16x8 __attribute__((ext_vector_type(8)));
typedef int   i32x4  __attribute__((ext_vector_type(4)));

#define IN_DIM   25088
#define OUT_DIM  4096
#define BATCH    64
#define SPLITS   28
#define KBLK     64
#define NBLK     14        // KBLK*NBLK = 896 = IN_DIM/SPLITS exactly
#define WG_N     128
#define LSTR     72        // LDS row stride in bf16 elems (64 + 8 pad, 16B-aligned)

#define CONV_BLOCKS 784    // convert_x: 784*256*8 = 64*25088 floats
#define PART_OFF   (4u << 20)   // partials at +4 MB in d_ws (xb is 3.2 MB)

// fp32 -> bf16 bits, round-to-nearest-even
__device__ __forceinline__ uint32_t f2bf(float f) {
    uint32_t u = __builtin_bit_cast(uint32_t, f);
    return (u + 0x7FFFu + ((u >> 16) & 1u)) >> 16;
}

// ---- kernel 1: x fp32 -> bf16 into d_ws ----
__global__ __launch_bounds__(256) void prep(const float* __restrict__ x,
                                            uint32_t* __restrict__ xb) {
    const size_t i = blockIdx.x * 256 + threadIdx.x;  // 8 floats -> 4 u32
    const float4 v0 = *(const float4*)(x + i * 8);
    const float4 v1 = *(const float4*)(x + i * 8 + 4);
    uint4 o;
    o.x = f2bf(v0.x) | (f2bf(v0.y) << 16);
    o.y = f2bf(v0.z) | (f2bf(v0.w) << 16);
    o.z = f2bf(v1.x) | (f2bf(v1.y) << 16);
    o.w = f2bf(v1.z) | (f2bf(v1.w) << 16);
    *(uint4*)(xb + i * 4) = o;
}

// ---- kernel 2: main GEMM (round -1 structure, verbatim), epilogue -> partials ----
__global__ __launch_bounds__(256) void qlinear_main(
    const int*      __restrict__ labels,    // [4096, 25088] int32 in [0,32)
    const float*    __restrict__ centroids, // [32]
    const uint16_t* __restrict__ xb,        // [64, 25088] bf16 (precomputed)
    float*          __restrict__ partials)  // [28][64][4096] fp32
{
    __shared__ __align__(16) uint32_t table[1024];       // pair dequant table
    __shared__ __align__(16) uint16_t wt[WG_N * LSTR];   // W tile [128][72] bf16
    __shared__ __align__(16) uint16_t xt[BATCH * LSTR];  // x tile [64][72] bf16

    const int t     = threadIdx.x;
    const int wgn   = blockIdx.x & 31;      // OUT_DIM / WG_N = 32 tiles
    const int split = blockIdx.x >> 5;      // 0..27
    const int o0    = wgn * WG_N;
    const int kbase = split * (KBLK * NBLK);

    // pair table: entry i = bf16(c[i&31]) | bf16(c[i>>5])<<16 (low = earlier k)
    #pragma unroll
    for (int e = 0; e < 4; ++e) {
        const int i = t + 256 * e;
        table[i] = f2bf(centroids[i & 31]) | (f2bf(centroids[i >> 5]) << 16);
    }

    const int lane = t & 63;
    const int wave = t >> 6;      // 0..3 -> 32 out-rows each
    const int ln   = lane & 15;
    const int lq   = lane >> 4;   // 0..3

    const int srow = t >> 3;        // W staging: 32 rows per pass
    const int skc  = (t & 7) * 8;   // 8 consecutive k per thread

    const int xrow = t >> 2;        // x staging: 64 rows, 4 threads/row
    const int xseg = (t & 3) * 16;  // 16 bf16 elems per thread

    // per-thread label base pointers (advance by KBLK each blk)
    const int* lbase[4];
    #pragma unroll
    for (int p = 0; p < 4; ++p)
        lbase[p] = labels + (size_t)(o0 + p * 32 + srow) * IN_DIM + kbase + skc;

    f32x4 acc[4][2] = {};   // [batch 16s][out 16s]

    // prologue: labels for blk 0 (nontemporal: 411 MB read-once stream)
    i32x4 pl[4][2];
    #pragma unroll
    for (int p = 0; p < 4; ++p) {
        pl[p][0] = __builtin_nontemporal_load((const i32x4*)lbase[p]);
        pl[p][1] = __builtin_nontemporal_load((const i32x4*)lbase[p] + 1);
    }

    for (int blk = 0; blk < NBLK; ++blk) {
        const int k0 = kbase + blk * KBLK;

        // prefetch blk+1 labels: issued a full iteration ahead of use
        i32x4 npl[4][2];
        if (blk + 1 < NBLK) {
            #pragma unroll
            for (int p = 0; p < 4; ++p) {
                const i32x4* lp = (const i32x4*)(lbase[p] + (blk + 1) * KBLK);
                npl[p][0] = __builtin_nontemporal_load(lp);
                npl[p][1] = __builtin_nontemporal_load(lp + 1);
            }
        }

        __syncthreads();   // wt/xt safe to overwrite (covers table build on blk==0)

        // ---- stage W tile from pl via pair table ----
        #pragma unroll
        for (int p = 0; p < 4; ++p) {
            const int row = p * 32 + srow;
            uint4 w;
            w.x = table[(uint32_t)pl[p][0].x | ((uint32_t)pl[p][0].y << 5)];
            w.y = table[(uint32_t)pl[p][0].z | ((uint32_t)pl[p][0].w << 5)];
            w.z = table[(uint32_t)pl[p][1].x | ((uint32_t)pl[p][1].y << 5)];
            w.w = table[(uint32_t)pl[p][1].z | ((uint32_t)pl[p][1].w << 5)];
            *(uint4*)(wt + row * LSTR + skc) = w;
        }
        // ---- stage x tile: bf16 copy (temporal: xb is L2-resident, reused) ----
        {
            const uint16_t* xp = xb + (size_t)xrow * IN_DIM + k0 + xseg;
            const bf16x8 v0 = *(const bf16x8*)xp;
            const bf16x8 v1 = *(const bf16x8*)(xp + 8);
            *(bf16x8*)(xt + xrow * LSTR + xseg)     = v0;
            *(bf16x8*)(xt + xrow * LSTR + xseg + 8) = v1;
        }
        __syncthreads();

        // ---- consume: 2 k-steps of 32, MFMA 16x16x32 bf16 ----
        #pragma unroll
        for (int ks = 0; ks < 2; ++ks) {
            const int kk = ks * 32 + lq * 8;   // frag: m/n = lane&15, k = (lane>>4)*8+j
            bf16x8 a[4], b[2];
            #pragma unroll
            for (int mt = 0; mt < 4; ++mt)
                a[mt] = *(const bf16x8*)(xt + (mt * 16 + ln) * LSTR + kk);
            #pragma unroll
            for (int nt = 0; nt < 2; ++nt)
                b[nt] = *(const bf16x8*)(wt + (wave * 32 + nt * 16 + ln) * LSTR + kk);
            #pragma unroll
            for (int mt = 0; mt < 4; ++mt)
                #pragma unroll
                for (int nt = 0; nt < 2; ++nt)
                    acc[mt][nt] = __builtin_amdgcn_mfma_f32_16x16x32_bf16(
                        a[mt], b[nt], acc[mt][nt], 0, 0, 0);
        }

        // rotate prefetch registers
        #pragma unroll
        for (int p = 0; p < 4; ++p) {
            pl[p][0] = npl[p][0];
            pl[p][1] = npl[p][1];
        }
    }

    // ---- epilogue: C/D layout col=lane&15 (out), row=(lane>>4)*4+reg (batch).
    // A/B experiment vs atomics: plain NT stores into per-split partials;
    // a separate tiny reduce kernel folds the 28 splits + bias into out.
    float* pout = partials + (size_t)split * BATCH * OUT_DIM;
    #pragma unroll
    for (int mt = 0; mt < 4; ++mt)
        #pragma unroll
        for (int nt = 0; nt < 2; ++nt) {
            const int o = o0 + wave * 32 + nt * 16 + ln;
            #pragma unroll
            for (int r = 0; r < 4; ++r)
                __builtin_nontemporal_store(
                    acc[mt][nt][r],
                    pout + (size_t)(mt * 16 + lq * 4 + r) * OUT_DIM + o);
        }
}

// ---- kernel 3: out[b][o] = bias[o] + sum_s partials[s][b][o] ----
__global__ __launch_bounds__(256) void reduce_out(
    const float* __restrict__ partials,
    const float* __restrict__ bias,
    float*       __restrict__ out) {
    const int g  = blockIdx.x * 256 + threadIdx.x;   // float4 id, 65536 total
    const int o4 = g & (OUT_DIM / 4 - 1);
    f32x4 s = *((const f32x4*)bias + o4);
    const f32x4* p = (const f32x4*)partials + g;
    #pragma unroll
    for (int sp = 0; sp < SPLITS; ++sp)
        s += p[(size_t)sp * (BATCH * OUT_DIM / 4)];
    *((f32x4*)out + g) = s;
}

extern "C" void kernel_launch(void* const* d_in, const int* in_sizes, int n_in,
                              void* d_out, int out_size, void* d_ws, size_t ws_size,
                              hipStream_t stream) {
    const float* x         = (const float*)d_in[0];
    const int*   labels    = (const int*)d_in[1];
    const float* centroids = (const float*)d_in[2];
    const float* bias      = (const float*)d_in[3];
    float* out = (float*)d_out;

    uint32_t* xb       = (uint32_t*)d_ws;                    // 3.2 MB bf16 x
    float*    partials = (float*)((char*)d_ws + PART_OFF);   // 29.4 MB

    prep<<<CONV_BLOCKS, 256, 0, stream>>>(x, xb);
    qlinear_main<<<32 * SPLITS, 256, 0, stream>>>(labels, centroids,
                                                  (const uint16_t*)xb, partials);
    reduce_out<<<BATCH * OUT_DIM / 4 / 256, 256, 0, stream>>>(partials, bias, out);
}